// Round 11
// baseline (755.512 us; speedup 1.0000x reference)
//
#include <hip/hip_runtime.h>
#include <math.h>

#define BQ 1024
#define TT 128
#define DD 128
#define HH 256
#define NTH 1024
#define NBLK 64

typedef float f32x4 __attribute__((ext_vector_type(4)));
typedef __bf16 bf16x8 __attribute__((ext_vector_type(8)));
typedef unsigned short u16x4 __attribute__((ext_vector_type(4)));
typedef unsigned short u16x8 __attribute__((ext_vector_type(8)));
typedef unsigned int u32x4 __attribute__((ext_vector_type(4)));
typedef unsigned int u32x2 __attribute__((ext_vector_type(2)));
typedef long long i64;

// ---- ws layout (bytes) ----
#define WS_MSUMF 8192        // float index: wsf[8192..8319] = 1/(msum+1e-5)
#define WS_WQ8   40960       // 864 fp8 tiles * 512 B
#define WS_WB16  487424      // 96 bf16 tiles * 1024 B
#define WS_SAG   589824      // saG : [t][blk][tid1024] u32    = 33554432 B -> 34144256
#define WS_SAXM  34144256    // saXM: [t][blk][tid512] u32x4   = 67108864 B -> 101253120
#define WS_SAB3  101253120   // saB3: [t][blk][tid1024] 3xu32  = 100663296 B -> 201916416

// fp8 tile map in wq (tile = 512 B):
//  [0,384):   Whh   [(g*16+nt)*8+kt]
//  [384,576): Wih_x [(g*16+nt)*4+kt]  (cols 0..127)
//  [576,640): Whist [nt*8+kt]
//  [640,672): Wr    [nt*4+kt] diag0
//  [672,864): Wih_m [(g*16+nt)*4+kt]  (cols 128..255)
#define TQ_TOT  864
#define TB_DEC 0
#define TB_WV  64
#define TB_TOT 96

// ---- scan LDS map (bytes) ----
#define L_WX  0        // wihx 192*512 = 98304
#define L_HI  98304    // hist 64*512 = 32768
#define L_WR  131072   // wr 32*512 = 16384
#define L_HF8 147456   // h' fp8 A-frags [8 kt][64][8] = 4096
#define L_XRF 151552   // x_r fp8 frags = 2048
#define L_XIF 153600   // x_imp fp8 frags = 2048
#define L_IMS 155648   // 128 f32 inv-msum
#define L_RED 156160   // 16 f32
#define L_TOT 156224

__device__ __forceinline__ unsigned short f2bf(float f){
  union { float f; unsigned u; } v; v.f = f;
  unsigned r = v.u + 0x7FFFu + ((v.u >> 16) & 1u);
  return (unsigned short)(r >> 16);
}
__device__ __forceinline__ float bf2f(unsigned short u){
  union { unsigned u; float f; } v; v.u = ((unsigned)u) << 16; return v.f;
}
__device__ __forceinline__ float sigm(float v){ return 1.f/(1.f + __expf(-v)); }
__device__ __forceinline__ float tanhfast(float v){ return 2.f*sigm(2.f*v) - 1.f; }
__device__ __forceinline__ unsigned pk4(float a, float b, float c, float d){
  int v = __builtin_amdgcn_cvt_pk_fp8_f32(a, b, 0, false);
  v = __builtin_amdgcn_cvt_pk_fp8_f32(c, d, v, true);
  return (unsigned)v;
}
__device__ __forceinline__ f32x4 upk4(unsigned w){
  f32x4 r;
  r[0] = __builtin_amdgcn_cvt_f32_fp8((int)w, 0);
  r[1] = __builtin_amdgcn_cvt_f32_fp8((int)w, 1);
  r[2] = __builtin_amdgcn_cvt_f32_fp8((int)w, 2);
  r[3] = __builtin_amdgcn_cvt_f32_fp8((int)w, 3);
  return r;
}
__device__ __forceinline__ f32x4 mfma8(i64 a, i64 b, f32x4 c){
  return __builtin_amdgcn_mfma_f32_16x16x32_fp8_fp8(a, b, c, 0, 0, 0);
}
__device__ __forceinline__ f32x4 mfma16b(bf16x8 a, bf16x8 b, f32x4 c){
  return __builtin_amdgcn_mfma_f32_16x16x32_bf16(a, b, c, 0, 0, 0);
}

// ---------------- pack fp8 weight tiles ----------------
__global__ void pack_w8(const float* Whh, const float* Wih, const float* Whist,
                        const float* Wr, unsigned char* wq){
  int gt = blockIdx.x*4 + (threadIdx.x>>6);
  int lane = threadIdx.x & 63;
  if (gt >= TQ_TOT) return;
  int lr = lane & 15, lg = lane >> 4;
  const float* src; int n, k0, K; int dm = 0;
  if (gt < 384){ int kt = gt & 7, gnt = gt >> 3;
    n = (gnt>>4)*256 + (gnt&15)*16 + lr; k0 = kt*32 + lg*8; src = Whh; K = 256; }
  else if (gt < 576){ int id = gt-384; int kt = id & 3, gnt = id >> 2;
    n = (gnt>>4)*256 + (gnt&15)*16 + lr; k0 = kt*32 + lg*8; src = Wih; K = 256; }
  else if (gt < 640){ int id = gt-576; int kt = id & 7, nt = id >> 3;
    n = nt*16 + lr; k0 = kt*32 + lg*8; src = Whist; K = 256; }
  else if (gt < 672){ int id = gt-640; int kt = id & 3, nt = id >> 2;
    n = nt*16 + lr; k0 = kt*32 + lg*8; src = Wr; K = 128; dm = 1; }
  else { int id = gt-672; int kt = id & 3, gnt = id >> 2;
    n = (gnt>>4)*256 + (gnt&15)*16 + lr; k0 = 128 + kt*32 + lg*8; src = Wih; K = 256; }
  float f[8];
  #pragma unroll
  for (int e = 0; e < 8; ++e){
    int k = k0 + e;
    float v = src[(size_t)n*K + k];
    if (dm && n == k) v = 0.f;
    f[e] = v;
  }
  unsigned lo = pk4(f[0],f[1],f[2],f[3]), hi = pk4(f[4],f[5],f[6],f[7]);
  *(unsigned*)(wq + (size_t)gt*512 + lane*8) = lo;
  *(unsigned*)(wq + (size_t)gt*512 + lane*8 + 4) = hi;
}

// ---------------- pack bf16 tiles (prep weights) ----------------
__global__ void pack_w16(const float* Wdec, const float* Wv, unsigned short* wb){
  int gt = blockIdx.x*4 + (threadIdx.x>>6);
  int lane = threadIdx.x & 63;
  if (gt >= TB_TOT) return;
  int lr = lane & 15, lg = lane >> 4;
  const float* src; int n; int dm = 0; int kt;
  if (gt < TB_WV){ kt = gt & 3; n = (gt>>2)*16 + lr; src = Wdec; }
  else { int id = gt - TB_WV; kt = id & 3; n = (id>>2)*16 + lr; src = Wv; dm = 1; }
  int k0 = kt*32 + lg*8;
  u16x8 pkv;
  #pragma unroll
  for (int e = 0; e < 8; ++e){
    int k = k0 + e;
    float v = src[(size_t)n*128 + k];
    if (dm && n == k) v = 0.f;
    pkv[e] = f2bf(v);
  }
  *(u16x8*)(wb + (size_t)gt*512 + lane*8) = pkv;
}

// ---------------- per-step inverse mask sums ----------------
__global__ void msum_kernel(const float* m, float* wsf){
  int t = blockIdx.x;
  float s = 0.f;
  for (int i = threadIdx.x; i < BQ*DD/4; i += 256){
    int b = i >> 5, c4 = (i & 31)*4;
    f32x4 v = *(const f32x4*)(m + ((size_t)b*TT + t)*DD + c4);
    s += v[0]+v[1]+v[2]+v[3];
  }
  #pragma unroll
  for (int off = 32; off >= 1; off >>= 1) s += __shfl_down(s, off);
  __shared__ float ps[4];
  if ((threadIdx.x & 63) == 0) ps[threadIdx.x >> 6] = s;
  __syncthreads();
  if (threadIdx.x == 0) wsf[WS_MSUMF + t] = 1.f/(ps[0]+ps[1]+ps[2]+ps[3] + 1e-5f);
}

// ---------------- final loss reduction (64 block partials) ----------------
__global__ void loss_final(const float* lossP, float* out_loss){
  float v = lossP[threadIdx.x];
  #pragma unroll
  for (int off = 32; off >= 1; off >>= 1) v += __shfl_down(v, off);
  if (threadIdx.x == 0) *out_loss = v;
}

// ---------------- prep: gamma/xu/mask/x/gim streams + out_xu ----------------
__global__ __launch_bounds__(512, 2) void prep_kernel(
    const float* __restrict__ x, const float* __restrict__ xhat,
    const float* __restrict__ m, const float* __restrict__ dly,
    const float* __restrict__ b_dec, const float* __restrict__ bv,
    const float* __restrict__ b_ih, const float* __restrict__ b_hh,
    const unsigned short* __restrict__ wb, const unsigned char* __restrict__ wq,
    unsigned* __restrict__ saG, unsigned* __restrict__ saXM,
    unsigned* __restrict__ saB3, float* __restrict__ out_xu)
{
  __shared__ __align__(16) char sm[18432]; // d-frag 4K | xb-frag 4K | m rowmaj 4K | m-frag 2K | x rowmaj 4K
  const int tid = threadIdx.x, w = tid>>6, lane = tid&63, lr = lane&15, lg = lane>>4;
  const int btile = blockIdx.x >> 4, tch = blockIdx.x & 15, b0 = btile*16;
  const int tg0 = tch*8;
  const int colD = w*16 + lr, colH0 = w*32 + lr;
  bf16x8 decR[2][4], wvR[4];
  #pragma unroll
  for (int s = 0; s < 2; ++s)
    #pragma unroll
    for (int kt = 0; kt < 4; ++kt)
      decR[s][kt] = *(const bf16x8*)(wb + (size_t)(TB_DEC + (w*2+s)*4 + kt)*512 + lane*8);
  #pragma unroll
  for (int kt = 0; kt < 4; ++kt)
    wvR[kt] = *(const bf16x8*)(wb + (size_t)(TB_WV + w*4 + kt)*512 + lane*8);
  i64 wihmR[6][4];
  float bfold[6];
  #pragma unroll
  for (int g = 0; g < 3; ++g)
    #pragma unroll
    for (int s = 0; s < 2; ++s){
      int j = g*2 + s;
      #pragma unroll
      for (int kt = 0; kt < 4; ++kt)
        wihmR[j][kt] = *(const i64*)(wq + (size_t)(672 + (g*16 + w*2+s)*4 + kt)*512 + lane*8);
      int n = g*256 + w*32 + s*16 + lr;
      bfold[j] = b_ih[n] + ((g < 2) ? b_hh[n] : 0.f);
    }
  const float bd0 = b_dec[colH0], bd1 = b_dec[colH0+16], bvv = bv[colD];
  const int srow = tid >> 5, c4 = (tid & 31)*4;
  const int kt_ = c4 >> 5, dl_ = ((c4 & 31) >> 3)*16 + srow, e0_ = c4 & 7;
  const size_t gbase = (size_t)(b0 + srow)*TT*DD + c4;

  f32x4 xv = *(const f32x4*)(x    + gbase + (size_t)tg0*DD);
  f32x4 hv = *(const f32x4*)(xhat + gbase + (size_t)tg0*DD);
  f32x4 mv = *(const f32x4*)(m    + gbase + (size_t)tg0*DD);
  f32x4 dv = *(const f32x4*)(dly  + gbase + (size_t)tg0*DD);

  for (int tt = 0; tt < 8; ++tt){
    int tg = tg0 + tt;
    u16x4 pd, pxb, pm, px;
    unsigned wbyte = 0;
    #pragma unroll
    for (int e = 0; e < 4; ++e){
      pd[e]  = f2bf(dv[e]);
      pxb[e] = f2bf(mv[e]*xv[e] + (1.f - mv[e])*hv[e]);
      pm[e]  = f2bf(mv[e]);
      px[e]  = f2bf(xv[e]);
      wbyte |= (mv[e] > 0.5f ? 0x38u : 0u) << (8*e);
    }
    *(u16x4*)(sm + 0     + kt_*1024 + dl_*16 + e0_*2) = pd;
    *(u16x4*)(sm + 4096  + kt_*1024 + dl_*16 + e0_*2) = pxb;
    *(u16x4*)(sm + 8192  + srow*256 + c4*2) = pm;
    *(unsigned*)(sm + 12288 + kt_*512 + dl_*8 + e0_) = wbyte;
    *(u16x4*)(sm + 14336 + srow*256 + c4*2) = px;
    __syncthreads();

    {
      size_t g2 = gbase + (size_t)((tt < 7) ? tg+1 : tg)*DD;
      xv = *(const f32x4*)(x + g2);
      hv = *(const f32x4*)(xhat + g2);
      mv = *(const f32x4*)(m + g2);
      dv = *(const f32x4*)(dly + g2);
    }

    f32x4 z4 = {0.f,0.f,0.f,0.f};
    f32x4 ga0 = z4, ga1 = z4, xu4 = z4;
    #pragma unroll
    for (int kt = 0; kt < 4; ++kt){
      bf16x8 df  = *(const bf16x8*)(sm + 0    + kt*1024 + lane*16);
      bf16x8 xbf = *(const bf16x8*)(sm + 4096 + kt*1024 + lane*16);
      ga0 = mfma16b(df, decR[0][kt], ga0);
      ga1 = mfma16b(df, decR[1][kt], ga1);
      xu4 = mfma16b(xbf, wvR[kt], xu4);
    }
    i64 ma[4];
    #pragma unroll
    for (int kt = 0; kt < 4; ++kt) ma[kt] = *(const i64*)(sm + 12288 + kt*512 + lane*8);
    f32x4 acc[6] = {z4,z4,z4,z4,z4,z4};
    #pragma unroll
    for (int j = 0; j < 6; ++j)
      #pragma unroll
      for (int kt = 0; kt < 4; ++kt)
        acc[j] = mfma8(ma[kt], wihmR[j][kt], acc[j]);

    float g0[4], g1[4], xuo[4];
    unsigned mask = 0;
    unsigned short x16[4];
    #pragma unroll
    for (int r = 0; r < 4; ++r){
      g0[r] = __expf(-fmaxf(ga0[r] + bd0, 0.f));
      g1[r] = __expf(-fmaxf(ga1[r] + bd1, 0.f));
      xuo[r] = xu4[r] + bvv;
      int row = lg*4 + r;
      unsigned short mu = *(const unsigned short*)(sm + 8192 + row*256 + colD*2);
      x16[r] = *(const unsigned short*)(sm + 14336 + row*256 + colD*2);
      mask |= (mu ? 1u : 0u) << r;
    }
    size_t base1024 = ((size_t)tg*NBLK + btile)*1024;
    __builtin_nontemporal_store(pk4(g0[0],g0[1],g0[2],g0[3]),
        saG + base1024 + (2*w+0)*64 + lane);
    __builtin_nontemporal_store(pk4(g1[0],g1[1],g1[2],g1[3]),
        saG + base1024 + (2*w+1)*64 + lane);
    u32x4 xmrec = {pk4(xuo[0],xuo[1],xuo[2],xuo[3]), mask,
                   (unsigned)x16[0] | ((unsigned)x16[1] << 16),
                   (unsigned)x16[2] | ((unsigned)x16[3] << 16)};
    __builtin_nontemporal_store(xmrec,
        (u32x4*)(saXM + (((size_t)tg*NBLK + btile)*512 + tid)*4));
    #pragma unroll
    for (int s = 0; s < 2; ++s){
      size_t bb = (base1024 + (2*w+s)*64 + lane)*3;
      #pragma unroll
      for (int g = 0; g < 3; ++g){
        f32x4 a = acc[g*2+s];
        __builtin_nontemporal_store(
            pk4(a[0]+bfold[g*2+s], a[1]+bfold[g*2+s], a[2]+bfold[g*2+s], a[3]+bfold[g*2+s]),
            saB3 + bb + g);
      }
    }
    #pragma unroll
    for (int r = 0; r < 4; ++r)
      __builtin_nontemporal_store(xuo[r], out_xu + ((size_t)(b0 + lg*4 + r)*TT + tg)*DD + colD);
    __syncthreads();
  }
}

// ---------------- the weight-stationary recurrent scan (16-wave split) ----------------
__global__ void __launch_bounds__(NTH, 4) scan_kernel(
    const unsigned char* __restrict__ wq,
    const unsigned* __restrict__ saG, const unsigned* __restrict__ saXM,
    const unsigned* __restrict__ saB3,
    const float* __restrict__ msumInv,
    const float* __restrict__ b_hist, const float* __restrict__ br,
    const float* __restrict__ b_hh,
    const float* __restrict__ conv_w, const float* __restrict__ conv_b,
    const float* __restrict__ W_out, const float* __restrict__ b_out,
    float* __restrict__ lossP,
    float* __restrict__ out_ximp, float* __restrict__ out_y,
    float* __restrict__ out_ys, float* __restrict__ out_xrs)
{
  extern __shared__ __align__(16) char lds[];
  const int tid = threadIdx.x, w = tid>>6, lane = tid&63, lr = lane&15, lg = lane>>4;
  const int b0 = blockIdx.x*16;
  const int wD = w & 7;
  const int colH = w*16 + lr;
  const int colD = wD*16 + lr;
  const bool isLo = (w < 8);

  // per-wave Whh slice (fp8): 24 i64 = 48 VGPR — pinned resident via asm
  i64 whhR[3][8];
  #pragma unroll
  for (int g = 0; g < 3; ++g)
    #pragma unroll
    for (int kt = 0; kt < 8; ++kt)
      whhR[g][kt] = *(const i64*)(wq + (size_t)((g*16 + w)*8 + kt)*512 + lane*8);
  // opacify: compiler cannot rematerialize these loads into the loop
  #pragma unroll
  for (int g = 0; g < 3; ++g)
    #pragma unroll
    for (int kt = 0; kt < 8; ++kt)
      asm volatile("" : "+v"(whhR[g][kt]));
  // LDS weights: wihx(192t) + hist(64t) + wr(32t) = tiles [384,672)
  for (int i = tid; i < 9216; i += NTH)
    *(u32x4*)(lds + (size_t)i*16) = *(const u32x4*)(wq + (size_t)384*512 + (size_t)i*16);
  if (tid < TT) *(float*)(lds + L_IMS + tid*4) = msumInv[tid];

  const float bhist_v = b_hist[colD], br_v = br[colD];
  const float bhhn = b_hh[512 + colH];
  const float cw0 = conv_w[0], cw1 = conv_w[1], cb = conv_b[0];

  const int hb16 = L_HF8 + (w>>1)*512 + ((w&1)*2 + (lr>>3))*128 + lg*32 + (lr&7);
  const int f80  = (wD>>1)*512 + ((wD&1)*2 + (lr>>3))*128 + lg*32 + (lr&7);

  float hs[4] = {0.f,0.f,0.f,0.f};
  float lacc = 0.f;

  const unsigned* pGp  = saG + (size_t)blockIdx.x*1024 + tid;
  const unsigned* pXMp = saXM + ((size_t)blockIdx.x*512 + wD*64 + lane)*4;
  const unsigned* pB3p = saB3 + ((size_t)blockIdx.x*1024 + tid)*3;
  const size_t STG = (size_t)NBLK*1024, STXM = (size_t)NBLK*2048, STB3 = (size_t)NBLK*3072;

  unsigned pG = __builtin_nontemporal_load(pGp);
  u32x4 pXM = __builtin_nontemporal_load((const u32x4*)pXMp);
  unsigned pR = __builtin_nontemporal_load(pB3p);
  unsigned pZ = __builtin_nontemporal_load(pB3p+1);
  unsigned pN = __builtin_nontemporal_load(pB3p+2);
  __syncthreads();

  #pragma unroll 1
  for (int t = 0; t < TT; ++t){
    // ---------- PH0: next-step loads; h *= gamma; stage h' fp8 frags ----------
    const unsigned* nGp  = (t < TT-1) ? (pGp + STG) : pGp;
    const unsigned* nXMp = (t < TT-1) ? (pXMp + STXM) : pXMp;
    const unsigned* nB3p = (t < TT-1) ? (pB3p + STB3) : pB3p;
    unsigned nG = __builtin_nontemporal_load(nGp);
    u32x4 nXM = __builtin_nontemporal_load((const u32x4*)nXMp);
    unsigned nR = __builtin_nontemporal_load(nB3p);
    unsigned nZ = __builtin_nontemporal_load(nB3p+1);
    unsigned nN = __builtin_nontemporal_load(nB3p+2);

    {
      f32x4 g4 = upk4(pG);
      #pragma unroll
      for (int r = 0; r < 4; ++r) hs[r] *= g4[r];
    }
    unsigned q0 = pk4(hs[0], hs[1], hs[2], hs[3]);
    #pragma unroll
    for (int r = 0; r < 4; ++r)
      *(unsigned char*)(lds + hb16 + r*8) = (unsigned char)(q0 >> (8*r));
    __syncthreads();  // B1

    // ---------- PH1: gh (whh regs, all waves); xh + x_r stage (waves 8-15) ----------
    f32x4 z4 = {0.f,0.f,0.f,0.f};
    f32x4 aR = z4, aZ = z4, aNh = z4;
    #pragma unroll
    for (int kt = 0; kt < 8; ++kt){
      i64 ha = *(const i64*)(lds + L_HF8 + kt*512 + lane*8);
      aR  = mfma8(ha, whhR[0][kt], aR);
      aZ  = mfma8(ha, whhR[1][kt], aZ);
      aNh = mfma8(ha, whhR[2][kt], aNh);
    }
    if (!isLo){
      f32x4 xh4 = z4;
      #pragma unroll
      for (int kt = 0; kt < 8; ++kt){
        i64 ha = *(const i64*)(lds + L_HF8 + kt*512 + lane*8);
        xh4 = mfma8(ha, *(const i64*)(lds + L_HI + (wD*8+kt)*512 + lane*8), xh4);
      }
      unsigned mk = pXM[1];
      float xf0 = bf2f((unsigned short)(pXM[2] & 0xffffu));
      float xf1 = bf2f((unsigned short)(pXM[2] >> 16));
      float xf2 = bf2f((unsigned short)(pXM[3] & 0xffffu));
      float xf3 = bf2f((unsigned short)(pXM[3] >> 16));
      float x0 = (mk & 1u) ? xf0 : (xh4[0] + bhist_v);
      float x1 = (mk & 2u) ? xf1 : (xh4[1] + bhist_v);
      float x2 = (mk & 4u) ? xf2 : (xh4[2] + bhist_v);
      float x3 = (mk & 8u) ? xf3 : (xh4[3] + bhist_v);
      unsigned p = pk4(x0, x1, x2, x3);
      #pragma unroll
      for (int r = 0; r < 4; ++r)
        *(unsigned char*)(lds + L_XRF + f80 + r*8) = (unsigned char)((p >> (8*r)) & 0xff);
    }
    __syncthreads();  // B2

    // ---------- PH2 (waves 0-7): xr; outputs; loss accum; x_imp stage ----------
    if (isLo){
      f32x4 xr4 = z4;
      #pragma unroll
      for (int kt = 0; kt < 4; ++kt)
        xr4 = mfma8(*(const i64*)(lds + L_XRF + kt*512 + lane*8),
                    *(const i64*)(lds + L_WR + (wD*4+kt)*512 + lane*8), xr4);
      unsigned mk = pXM[1];
      f32x4 xu4v = upk4(pXM[0]);
      float xf_[4];
      xf_[0] = bf2f((unsigned short)(pXM[2] & 0xffffu));
      xf_[1] = bf2f((unsigned short)(pXM[2] >> 16));
      xf_[2] = bf2f((unsigned short)(pXM[3] & 0xffffu));
      xf_[3] = bf2f((unsigned short)(pXM[3] >> 16));
      float ims = *(const float*)(lds + L_IMS + t*4);
      float lp = 0.f, xi_[4];
      #pragma unroll
      for (int r = 0; r < 4; ++r){
        int row = lg*4 + r;
        size_t go = ((size_t)(b0+row)*TT + t)*DD + colD;
        float xrv = xr4[r] + br_v;
        __builtin_nontemporal_store(xrv, out_xrs + go);
        float xc = cw0*xu4v[r] + cw1*xrv + cb;
        bool mb = (mk >> r) & 1u;
        lp += mb ? fabsf(xf_[r] - xc) : 0.f;
        xi_[r] = mb ? xf_[r] : xc;
        __builtin_nontemporal_store(xi_[r], out_ximp + go);
      }
      lacc += lp * ims;
      unsigned q = pk4(xi_[0], xi_[1], xi_[2], xi_[3]);
      #pragma unroll
      for (int r = 0; r < 4; ++r)
        *(unsigned char*)(lds + L_XIF + f80 + r*8) = (unsigned char)((q >> (8*r)) & 0xff);
    }
    __syncthreads();  // B3

    // ---------- PH3: gi_x (wihx LDS) + gates + h update (all waves) ----------
    f32x4 aNi = z4;
    #pragma unroll
    for (int kt = 0; kt < 4; ++kt){
      i64 xia = *(const i64*)(lds + L_XIF + kt*512 + lane*8);
      aR  = mfma8(xia, *(const i64*)(lds + L_WX + (( 0 + w)*4 + kt)*512 + lane*8), aR);
      aZ  = mfma8(xia, *(const i64*)(lds + L_WX + ((16 + w)*4 + kt)*512 + lane*8), aZ);
      aNi = mfma8(xia, *(const i64*)(lds + L_WX + ((32 + w)*4 + kt)*512 + lane*8), aNi);
    }
    {
      f32x4 gR4 = upk4(pR), gZ4 = upk4(pZ), gN4 = upk4(pN);
      #pragma unroll
      for (int r = 0; r < 4; ++r){
        float rr = sigm(aR[r] + gR4[r]);
        float zz = sigm(aZ[r] + gZ4[r]);
        float nn = tanhfast(aNi[r] + gN4[r] + rr*(aNh[r] + bhhn));
        hs[r] = (1.f - zz)*nn + zz*hs[r];
      }
    }
    pG = nG; pXM = nXM; pR = nR; pZ = nZ; pN = nN;
    pGp = nGp; pXMp = nXMp; pB3p = nB3p;
  }

  // ---------- epilogue: loss partial + y = h_fin @ W_out^T + b ----------
  __syncthreads();
  #pragma unroll
  for (int off = 32; off >= 1; off >>= 1) lacc += __shfl_down(lacc, off);
  if (lane == 0) ((float*)(lds + L_RED))[w] = lacc;
  float* hfin = (float*)lds;
  #pragma unroll
  for (int r = 0; r < 4; ++r)
    hfin[(lg*4+r)*HH + colH] = hs[r];
  __syncthreads();
  if (tid == 0){
    float s = 0.f;
    #pragma unroll
    for (int i = 0; i < 16; ++i) s += ((float*)(lds + L_RED))[i];
    lossP[blockIdx.x] = s;
  }
  float* psum = (float*)(lds + 16384);
  if (tid < 256){
    int row = tid >> 4, seg = tid & 15;
    float p = 0.f;
    #pragma unroll
    for (int c = 0; c < 16; ++c) p += hfin[row*HH + seg*16 + c]*W_out[seg*16 + c];
    psum[tid] = p;
  }
  __syncthreads();
  if (tid < 16){
    float yv = b_out[0];
    #pragma unroll
    for (int i = 0; i < 16; ++i) yv += psum[tid*16 + i];
    out_y[b0 + tid] = yv;
    out_ys[b0 + tid] = sigm(yv);
  }
}

extern "C" void kernel_launch(void* const* d_in, const int* in_sizes, int n_in,
                              void* d_out, int out_size, void* d_ws, size_t ws_size,
                              hipStream_t stream){
  const float* x     = (const float*)d_in[0];
  const float* xhat  = (const float*)d_in[1];
  const float* m     = (const float*)d_in[3];
  const float* dly   = (const float*)d_in[4];
  const float* Wdec  = (const float*)d_in[5];
  const float* b_dec = (const float*)d_in[6];
  const float* Whist = (const float*)d_in[7];
  const float* b_hist= (const float*)d_in[8];
  const float* Wv    = (const float*)d_in[9];
  const float* bvv   = (const float*)d_in[10];
  const float* Wr    = (const float*)d_in[11];
  const float* brr   = (const float*)d_in[12];
  const float* convw = (const float*)d_in[13];
  const float* convb = (const float*)d_in[14];
  const float* Wih   = (const float*)d_in[15];
  const float* Whh   = (const float*)d_in[16];
  const float* b_ih  = (const float*)d_in[17];
  const float* b_hh  = (const float*)d_in[18];
  const float* W_out = (const float*)d_in[19];
  const float* b_out = (const float*)d_in[20];

  float* wsf = (float*)d_ws;                 // [0..63] lossP, [8192..8319] inv-msums
  unsigned char* wq = (unsigned char*)d_ws + WS_WQ8;
  unsigned short* wb = (unsigned short*)((char*)d_ws + WS_WB16);
  unsigned* saG  = (unsigned*)((char*)d_ws + WS_SAG);
  unsigned* saXM = (unsigned*)((char*)d_ws + WS_SAXM);
  unsigned* saB3 = (unsigned*)((char*)d_ws + WS_SAB3);

  float* out = (float*)d_out;
  size_t btd = (size_t)BQ*TT*DD;
  float* out_ximp = out;
  float* out_y    = out + btd;
  float* out_ys   = out_y + BQ;
  float* out_loss = out_ys + BQ;
  float* out_xu   = out_loss + 1;
  float* out_xrs  = out_xu + btd;

  (void)hipFuncSetAttribute((const void*)scan_kernel,
                            hipFuncAttributeMaxDynamicSharedMemorySize, L_TOT);

  pack_w8<<<TQ_TOT/4, 256, 0, stream>>>(Whh, Wih, Whist, Wr, wq);
  pack_w16<<<TB_TOT/4, 256, 0, stream>>>(Wdec, Wv, wb);
  msum_kernel<<<TT, 256, 0, stream>>>(m, wsf);
  prep_kernel<<<1024, 512, 0, stream>>>(x, xhat, m, dly, b_dec, bvv, b_ih, b_hh,
      wb, wq, saG, saXM, saB3, out_xu);
  scan_kernel<<<NBLK, NTH, L_TOT, stream>>>(wq, saG, saXM, saB3, wsf + WS_MSUMF,
      b_hist, brr, b_hh, convw, convb, W_out, b_out, wsf,
      out_ximp, out_y, out_ys, out_xrs);
  loss_final<<<1, 64, 0, stream>>>(wsf, out_loss);
}

// Round 12
// 624.890 us; speedup vs baseline: 1.2090x; 1.2090x over previous
//
#include <hip/hip_runtime.h>
#include <math.h>

#define BQ 1024
#define TT 128
#define DD 128
#define HH 256
#define NW 8
#define NTH 512
#define NBLK 64

typedef float f32x4 __attribute__((ext_vector_type(4)));
typedef __bf16 bf16x8 __attribute__((ext_vector_type(8)));
typedef unsigned short u16x4 __attribute__((ext_vector_type(4)));
typedef unsigned short u16x8 __attribute__((ext_vector_type(8)));
typedef unsigned int u32x4 __attribute__((ext_vector_type(4)));
typedef unsigned int u32x2 __attribute__((ext_vector_type(2)));
typedef long long i64;

// ---- ws layout (bytes) ----
#define WS_MSUMF 8192        // float index: wsf[8192..8319] = 1/(msum+1e-5)
#define WS_WQ8   40960       // 864 fp8 tiles * 512 B
#define WS_WB16  487424      // 96 bf16 tiles * 1024 B
#define WS_SA1   589824      // saA: [t][blk][tid512] u32x4 = 67108864 -> 67698688
#define WS_SAX   67698688    // saX: [t][blk][tid512] u32x2 = 33554432 -> 101253120
#define WS_SA2   101253120   // saB: [t][blk][tid512] 6xu32 = 100663296 -> 201916416

// fp8 tile map in wq (tile = 512 B):
//  [0,384):   Whh   [(g*16+nt)*8+kt]
//  [384,576): Wih_x [(g*16+nt)*4+kt]  (cols 0..127)
//  [576,640): Whist [nt*8+kt]
//  [640,672): Wr    [nt*4+kt] diag0
//  [672,864): Wih_m [(g*16+nt)*4+kt]  (cols 128..255)
#define TQ_TOT  864
#define TB_DEC 0
#define TB_WV  64
#define TB_TOT 96

// ---- scan LDS map (bytes) ----
#define L_WX  0        // wihx 192*512 = 98304
#define L_HI  98304    // hist 64*512 = 32768
#define L_WR  131072   // wr 32*512 = 16384
#define L_HF8 147456   // h' fp8 A-frags [8 kt][64][8] = 4096
#define L_XRF 151552   // x_r fp8 frags = 2048
#define L_XIF 153600   // x_imp fp8 frags = 2048
#define L_IMS 155648   // 128 f32 inv-msum
#define L_RED 156160   // 16 f32
#define L_TOT 156224

__device__ __forceinline__ unsigned short f2bf(float f){
  union { float f; unsigned u; } v; v.f = f;
  unsigned r = v.u + 0x7FFFu + ((v.u >> 16) & 1u);
  return (unsigned short)(r >> 16);
}
__device__ __forceinline__ float bf2f(unsigned short u){
  union { unsigned u; float f; } v; v.u = ((unsigned)u) << 16; return v.f;
}
__device__ __forceinline__ float sigm(float v){ return 1.f/(1.f + __expf(-v)); }
__device__ __forceinline__ float tanhfast(float v){ return 2.f*sigm(2.f*v) - 1.f; }
__device__ __forceinline__ unsigned pk4(float a, float b, float c, float d){
  int v = __builtin_amdgcn_cvt_pk_fp8_f32(a, b, 0, false);
  v = __builtin_amdgcn_cvt_pk_fp8_f32(c, d, v, true);
  return (unsigned)v;
}
__device__ __forceinline__ f32x4 upk4(unsigned w){
  f32x4 r;
  r[0] = __builtin_amdgcn_cvt_f32_fp8((int)w, 0);
  r[1] = __builtin_amdgcn_cvt_f32_fp8((int)w, 1);
  r[2] = __builtin_amdgcn_cvt_f32_fp8((int)w, 2);
  r[3] = __builtin_amdgcn_cvt_f32_fp8((int)w, 3);
  return r;
}
__device__ __forceinline__ f32x4 mfma8(i64 a, i64 b, f32x4 c){
  return __builtin_amdgcn_mfma_f32_16x16x32_fp8_fp8(a, b, c, 0, 0, 0);
}
__device__ __forceinline__ f32x4 mfma16b(bf16x8 a, bf16x8 b, f32x4 c){
  return __builtin_amdgcn_mfma_f32_16x16x32_bf16(a, b, c, 0, 0, 0);
}

// ---------------- pack fp8 weight tiles ----------------
__global__ void pack_w8(const float* Whh, const float* Wih, const float* Whist,
                        const float* Wr, unsigned char* wq){
  int gt = blockIdx.x*4 + (threadIdx.x>>6);
  int lane = threadIdx.x & 63;
  if (gt >= TQ_TOT) return;
  int lr = lane & 15, lg = lane >> 4;
  const float* src; int n, k0, K; int dm = 0;
  if (gt < 384){ int kt = gt & 7, gnt = gt >> 3;
    n = (gnt>>4)*256 + (gnt&15)*16 + lr; k0 = kt*32 + lg*8; src = Whh; K = 256; }
  else if (gt < 576){ int id = gt-384; int kt = id & 3, gnt = id >> 2;
    n = (gnt>>4)*256 + (gnt&15)*16 + lr; k0 = kt*32 + lg*8; src = Wih; K = 256; }
  else if (gt < 640){ int id = gt-576; int kt = id & 7, nt = id >> 3;
    n = nt*16 + lr; k0 = kt*32 + lg*8; src = Whist; K = 256; }
  else if (gt < 672){ int id = gt-640; int kt = id & 3, nt = id >> 2;
    n = nt*16 + lr; k0 = kt*32 + lg*8; src = Wr; K = 128; dm = 1; }
  else { int id = gt-672; int kt = id & 3, gnt = id >> 2;
    n = (gnt>>4)*256 + (gnt&15)*16 + lr; k0 = 128 + kt*32 + lg*8; src = Wih; K = 256; }
  float f[8];
  #pragma unroll
  for (int e = 0; e < 8; ++e){
    int k = k0 + e;
    float v = src[(size_t)n*K + k];
    if (dm && n == k) v = 0.f;
    f[e] = v;
  }
  unsigned lo = pk4(f[0],f[1],f[2],f[3]), hi = pk4(f[4],f[5],f[6],f[7]);
  *(unsigned*)(wq + (size_t)gt*512 + lane*8) = lo;
  *(unsigned*)(wq + (size_t)gt*512 + lane*8 + 4) = hi;
}

// ---------------- pack bf16 tiles (prep weights) ----------------
__global__ void pack_w16(const float* Wdec, const float* Wv, unsigned short* wb){
  int gt = blockIdx.x*4 + (threadIdx.x>>6);
  int lane = threadIdx.x & 63;
  if (gt >= TB_TOT) return;
  int lr = lane & 15, lg = lane >> 4;
  const float* src; int n; int dm = 0; int kt;
  if (gt < TB_WV){ kt = gt & 3; n = (gt>>2)*16 + lr; src = Wdec; }
  else { int id = gt - TB_WV; kt = id & 3; n = (id>>2)*16 + lr; src = Wv; dm = 1; }
  int k0 = kt*32 + lg*8;
  u16x8 pkv;
  #pragma unroll
  for (int e = 0; e < 8; ++e){
    int k = k0 + e;
    float v = src[(size_t)n*128 + k];
    if (dm && n == k) v = 0.f;
    pkv[e] = f2bf(v);
  }
  *(u16x8*)(wb + (size_t)gt*512 + lane*8) = pkv;
}

// ---------------- per-step inverse mask sums ----------------
__global__ void msum_kernel(const float* m, float* wsf){
  int t = blockIdx.x;
  float s = 0.f;
  for (int i = threadIdx.x; i < BQ*DD/4; i += 256){
    int b = i >> 5, c4 = (i & 31)*4;
    f32x4 v = *(const f32x4*)(m + ((size_t)b*TT + t)*DD + c4);
    s += v[0]+v[1]+v[2]+v[3];
  }
  #pragma unroll
  for (int off = 32; off >= 1; off >>= 1) s += __shfl_down(s, off);
  __shared__ float ps[4];
  if ((threadIdx.x & 63) == 0) ps[threadIdx.x >> 6] = s;
  __syncthreads();
  if (threadIdx.x == 0) wsf[WS_MSUMF + t] = 1.f/(ps[0]+ps[1]+ps[2]+ps[3] + 1e-5f);
}

// ---------------- final loss reduction (64 block partials) ----------------
__global__ void loss_final(const float* lossP, float* out_loss){
  float v = lossP[threadIdx.x];
  #pragma unroll
  for (int off = 32; off >= 1; off >>= 1) v += __shfl_down(v, off);
  if (threadIdx.x == 0) *out_loss = v;
}

// ---------------- prep: gamma/xu/mask/x/gim streams + out_xu ----------------
__global__ __launch_bounds__(512, 2) void prep_kernel(
    const float* __restrict__ x, const float* __restrict__ xhat,
    const float* __restrict__ m, const float* __restrict__ dly,
    const float* __restrict__ b_dec, const float* __restrict__ bv,
    const float* __restrict__ b_ih, const float* __restrict__ b_hh,
    const unsigned short* __restrict__ wb, const unsigned char* __restrict__ wq,
    unsigned* __restrict__ saA, unsigned* __restrict__ saX,
    unsigned* __restrict__ saB, float* __restrict__ out_xu)
{
  __shared__ __align__(16) char sm[18432]; // d-frag 4K | xb-frag 4K | m rowmaj 4K | m-frag 2K | x rowmaj 4K
  const int tid = threadIdx.x, w = tid>>6, lane = tid&63, lr = lane&15, lg = lane>>4;
  const int btile = blockIdx.x >> 4, tch = blockIdx.x & 15, b0 = btile*16;
  const int tg0 = tch*8;
  const int colD = w*16 + lr, colH0 = w*32 + lr;
  bf16x8 decR[2][4], wvR[4];
  #pragma unroll
  for (int s = 0; s < 2; ++s)
    #pragma unroll
    for (int kt = 0; kt < 4; ++kt)
      decR[s][kt] = *(const bf16x8*)(wb + (size_t)(TB_DEC + (w*2+s)*4 + kt)*512 + lane*8);
  #pragma unroll
  for (int kt = 0; kt < 4; ++kt)
    wvR[kt] = *(const bf16x8*)(wb + (size_t)(TB_WV + w*4 + kt)*512 + lane*8);
  i64 wihmR[6][4];
  float bfold[6];
  #pragma unroll
  for (int g = 0; g < 3; ++g)
    #pragma unroll
    for (int s = 0; s < 2; ++s){
      int j = g*2 + s;
      #pragma unroll
      for (int kt = 0; kt < 4; ++kt)
        wihmR[j][kt] = *(const i64*)(wq + (size_t)(672 + (g*16 + w*2+s)*4 + kt)*512 + lane*8);
      int n = g*256 + w*32 + s*16 + lr;
      bfold[j] = b_ih[n] + ((g < 2) ? b_hh[n] : 0.f);
    }
  const float bd0 = b_dec[colH0], bd1 = b_dec[colH0+16], bvv = bv[colD];
  const int srow = tid >> 5, c4 = (tid & 31)*4;
  const int kt_ = c4 >> 5, dl_ = ((c4 & 31) >> 3)*16 + srow, e0_ = c4 & 7;
  const size_t gbase = (size_t)(b0 + srow)*TT*DD + c4;

  f32x4 xv = *(const f32x4*)(x    + gbase + (size_t)tg0*DD);
  f32x4 hv = *(const f32x4*)(xhat + gbase + (size_t)tg0*DD);
  f32x4 mv = *(const f32x4*)(m    + gbase + (size_t)tg0*DD);
  f32x4 dv = *(const f32x4*)(dly  + gbase + (size_t)tg0*DD);

  for (int tt = 0; tt < 8; ++tt){
    int tg = tg0 + tt;
    u16x4 pd, pxb, pm, px;
    unsigned wbyte = 0;
    #pragma unroll
    for (int e = 0; e < 4; ++e){
      pd[e]  = f2bf(dv[e]);
      pxb[e] = f2bf(mv[e]*xv[e] + (1.f - mv[e])*hv[e]);
      pm[e]  = f2bf(mv[e]);
      px[e]  = f2bf(xv[e]);
      wbyte |= (mv[e] > 0.5f ? 0x38u : 0u) << (8*e);
    }
    *(u16x4*)(sm + 0     + kt_*1024 + dl_*16 + e0_*2) = pd;
    *(u16x4*)(sm + 4096  + kt_*1024 + dl_*16 + e0_*2) = pxb;
    *(u16x4*)(sm + 8192  + srow*256 + c4*2) = pm;
    *(unsigned*)(sm + 12288 + kt_*512 + dl_*8 + e0_) = wbyte;
    *(u16x4*)(sm + 14336 + srow*256 + c4*2) = px;
    __syncthreads();

    {
      size_t g2 = gbase + (size_t)((tt < 7) ? tg+1 : tg)*DD;
      xv = *(const f32x4*)(x + g2);
      hv = *(const f32x4*)(xhat + g2);
      mv = *(const f32x4*)(m + g2);
      dv = *(const f32x4*)(dly + g2);
    }

    f32x4 z4 = {0.f,0.f,0.f,0.f};
    f32x4 ga0 = z4, ga1 = z4, xu4 = z4;
    #pragma unroll
    for (int kt = 0; kt < 4; ++kt){
      bf16x8 df  = *(const bf16x8*)(sm + 0    + kt*1024 + lane*16);
      bf16x8 xbf = *(const bf16x8*)(sm + 4096 + kt*1024 + lane*16);
      ga0 = mfma16b(df, decR[0][kt], ga0);
      ga1 = mfma16b(df, decR[1][kt], ga1);
      xu4 = mfma16b(xbf, wvR[kt], xu4);
    }
    i64 ma[4];
    #pragma unroll
    for (int kt = 0; kt < 4; ++kt) ma[kt] = *(const i64*)(sm + 12288 + kt*512 + lane*8);
    f32x4 acc[6] = {z4,z4,z4,z4,z4,z4};
    #pragma unroll
    for (int j = 0; j < 6; ++j)
      #pragma unroll
      for (int kt = 0; kt < 4; ++kt)
        acc[j] = mfma8(ma[kt], wihmR[j][kt], acc[j]);

    float g0[4], g1[4], xuo[4];
    unsigned mask = 0;
    unsigned short x16[4];
    #pragma unroll
    for (int r = 0; r < 4; ++r){
      g0[r] = __expf(-fmaxf(ga0[r] + bd0, 0.f));
      g1[r] = __expf(-fmaxf(ga1[r] + bd1, 0.f));
      xuo[r] = xu4[r] + bvv;
      int row = lg*4 + r;
      unsigned short mu = *(const unsigned short*)(sm + 8192 + row*256 + colD*2);
      x16[r] = *(const unsigned short*)(sm + 14336 + row*256 + colD*2);
      mask |= (mu ? 1u : 0u) << r;
    }
    size_t recb = ((size_t)tg*NBLK + btile)*512 + tid;
    u32x4 rec = {pk4(g0[0],g0[1],g0[2],g0[3]), pk4(g1[0],g1[1],g1[2],g1[3]),
                 pk4(xuo[0],xuo[1],xuo[2],xuo[3]), mask};
    __builtin_nontemporal_store(rec, (u32x4*)(saA + recb*4));
    u32x2 xrec = {(unsigned)x16[0] | ((unsigned)x16[1] << 16),
                  (unsigned)x16[2] | ((unsigned)x16[3] << 16)};
    __builtin_nontemporal_store(xrec, (u32x2*)(saX + recb*2));
    unsigned wd[6];
    #pragma unroll
    for (int j = 0; j < 6; ++j)
      wd[j] = pk4(acc[j][0]+bfold[j], acc[j][1]+bfold[j], acc[j][2]+bfold[j], acc[j][3]+bfold[j]);
    u32x2 p0 = {wd[0], wd[1]}, p1 = {wd[2], wd[3]}, p2 = {wd[4], wd[5]};
    __builtin_nontemporal_store(p0, (u32x2*)(saB + recb*6));
    __builtin_nontemporal_store(p1, (u32x2*)(saB + recb*6 + 2));
    __builtin_nontemporal_store(p2, (u32x2*)(saB + recb*6 + 4));
    #pragma unroll
    for (int r = 0; r < 4; ++r)
      __builtin_nontemporal_store(xuo[r], out_xu + ((size_t)(b0 + lg*4 + r)*TT + tg)*DD + colD);
    __syncthreads();
  }
}

// ---------------- the weight-stationary recurrent scan (R7 structure) ----------------
__global__ __launch_bounds__(NTH) __attribute__((amdgpu_waves_per_eu(2, 2)))
void scan_kernel(
    const unsigned char* __restrict__ wq, const unsigned* __restrict__ saA,
    const unsigned* __restrict__ saX, const unsigned* __restrict__ saB,
    const float* __restrict__ msumInv,
    const float* __restrict__ b_hist, const float* __restrict__ br,
    const float* __restrict__ b_hh,
    const float* __restrict__ conv_w, const float* __restrict__ conv_b,
    const float* __restrict__ W_out, const float* __restrict__ b_out,
    float* __restrict__ lossP,
    float* __restrict__ out_ximp, float* __restrict__ out_y,
    float* __restrict__ out_ys, float* __restrict__ out_xrs)
{
  extern __shared__ __align__(16) char lds[];
  const int tid = threadIdx.x, w = tid>>6, lane = tid&63, lr = lane&15, lg = lane>>4;
  const int b0 = blockIdx.x*16;
  const int colD = w*16 + lr, colH0 = w*32 + lr;

  // register-resident Whh (fp8): 48 i64 = 96 VGPR
  i64 whhR[3][2][8];
  #pragma unroll
  for (int g = 0; g < 3; ++g)
    #pragma unroll
    for (int s = 0; s < 2; ++s)
      #pragma unroll
      for (int kt = 0; kt < 8; ++kt)
        whhR[g][s][kt] = *(const i64*)(wq + (size_t)((g*16 + w*2+s)*8 + kt)*512 + lane*8);
  // LDS weights: wihx(192t) + hist(64t) + wr(32t) = tiles [384,672)
  for (int i = tid; i < 9216; i += NTH)
    *(u32x4*)(lds + (size_t)i*16) = *(const u32x4*)(wq + (size_t)384*512 + (size_t)i*16);
  if (tid < TT) *(float*)(lds + L_IMS + tid*4) = msumInv[tid];

  const float bhist_v = b_hist[colD], br_v = br[colD];
  const float bhhn0 = b_hh[512 + colH0], bhhn1 = b_hh[512 + colH0 + 16];
  const float cw0 = conv_w[0], cw1 = conv_w[1], cb = conv_b[0];

  const int hb0 = L_HF8 + w*512 + (lr>>3)*128 + lg*32 + (lr&7);           // + s*256 + r*8
  const int f80 = (w>>1)*512 + ((w&1)*2 + (lr>>3))*128 + lg*32 + (lr&7);  // + r*8
  float* red = (float*)(lds + L_RED);

  float hs[2][4] = {{0.f,0.f,0.f,0.f},{0.f,0.f,0.f,0.f}};
  float lacc = 0.f;

  const unsigned* rpa = saA + ((size_t)blockIdx.x*512 + tid)*4;
  const unsigned* rpx = saX + ((size_t)blockIdx.x*512 + tid)*2;
  const unsigned* rpb = saB + ((size_t)blockIdx.x*512 + tid)*6;
  const size_t STA = (size_t)NBLK*512*4, STX = (size_t)NBLK*512*2, STB = (size_t)NBLK*512*6;

  u32x4 pfA = __builtin_nontemporal_load((const u32x4*)rpa);
  u32x2 pfX = __builtin_nontemporal_load((const u32x2*)rpx);
  u32x2 pfB0 = __builtin_nontemporal_load((const u32x2*)rpb);
  u32x2 pfB1 = __builtin_nontemporal_load((const u32x2*)(rpb+2));
  u32x2 pfB2 = __builtin_nontemporal_load((const u32x2*)(rpb+4));
  __syncthreads();

  #pragma unroll 1
  for (int t = 0; t < TT; ++t){
    // ---------- PH0: next-step loads; h *= gamma; stage h' fp8 frags ----------
    const unsigned* npa = (t < TT-1) ? (rpa + STA) : rpa;
    const unsigned* npx = (t < TT-1) ? (rpx + STX) : rpx;
    const unsigned* npb = (t < TT-1) ? (rpb + STB) : rpb;
    u32x4 nA = __builtin_nontemporal_load((const u32x4*)npa);
    u32x2 nX = __builtin_nontemporal_load((const u32x2*)npx);
    u32x2 nB0 = __builtin_nontemporal_load((const u32x2*)npb);
    u32x2 nB1 = __builtin_nontemporal_load((const u32x2*)(npb+2));
    u32x2 nB2 = __builtin_nontemporal_load((const u32x2*)(npb+4));

    {
      f32x4 gA0 = upk4(pfA[0]), gA1 = upk4(pfA[1]);
      #pragma unroll
      for (int r = 0; r < 4; ++r){
        hs[0][r] *= gA0[r];
        hs[1][r] *= gA1[r];
      }
    }
    unsigned q0 = pk4(hs[0][0], hs[0][1], hs[0][2], hs[0][3]);
    unsigned q1 = pk4(hs[1][0], hs[1][1], hs[1][2], hs[1][3]);
    #pragma unroll
    for (int r = 0; r < 4; ++r){
      *(unsigned char*)(lds + hb0 +       r*8) = (unsigned char)(q0 >> (8*r));
      *(unsigned char*)(lds + hb0 + 256 + r*8) = (unsigned char)(q1 >> (8*r));
    }
    __syncthreads();  // B1

    // ---------- PH1: gh (whh regs) + xh (hist LDS); x_r -> XRF ----------
    i64 ha[8];
    #pragma unroll
    for (int kt = 0; kt < 8; ++kt)
      ha[kt] = *(const i64*)(lds + L_HF8 + kt*512 + lane*8);
    f32x4 z4 = {0.f,0.f,0.f,0.f};
    f32x4 aRZ[2][2] = {{z4,z4},{z4,z4}};
    f32x4 aNh[2] = {z4,z4}, aNi[2] = {z4,z4}, xh4 = z4;
    __builtin_amdgcn_s_setprio(1);
    #pragma unroll
    for (int s = 0; s < 2; ++s)
      #pragma unroll
      for (int kt = 0; kt < 8; ++kt){
        aRZ[0][s] = mfma8(ha[kt], whhR[0][s][kt], aRZ[0][s]);
        aRZ[1][s] = mfma8(ha[kt], whhR[1][s][kt], aRZ[1][s]);
        aNh[s]    = mfma8(ha[kt], whhR[2][s][kt], aNh[s]);
      }
    #pragma unroll
    for (int kt = 0; kt < 8; ++kt)
      xh4 = mfma8(ha[kt], *(const i64*)(lds + L_HI + (w*8+kt)*512 + lane*8), xh4);
    __builtin_amdgcn_s_setprio(0);
    {
      unsigned mk = pfA[3];
      float xf0 = bf2f((unsigned short)(pfX[0] & 0xffffu));
      float xf1 = bf2f((unsigned short)(pfX[0] >> 16));
      float xf2 = bf2f((unsigned short)(pfX[1] & 0xffffu));
      float xf3 = bf2f((unsigned short)(pfX[1] >> 16));
      float x0 = (mk & 1u) ? xf0 : (xh4[0] + bhist_v);
      float x1 = (mk & 2u) ? xf1 : (xh4[1] + bhist_v);
      float x2 = (mk & 4u) ? xf2 : (xh4[2] + bhist_v);
      float x3 = (mk & 8u) ? xf3 : (xh4[3] + bhist_v);
      unsigned p = pk4(x0, x1, x2, x3);
      #pragma unroll
      for (int r = 0; r < 4; ++r)
        *(unsigned char*)(lds + L_XRF + f80 + r*8) = (unsigned char)((p >> (8*r)) & 0xff);
    }
    __syncthreads();  // B2

    // ---------- PH2: xr (wr LDS); outputs; loss accum; x_imp -> XIF ----------
    f32x4 xr4 = z4;
    __builtin_amdgcn_s_setprio(1);
    #pragma unroll
    for (int kt = 0; kt < 4; ++kt)
      xr4 = mfma8(*(const i64*)(lds + L_XRF + kt*512 + lane*8),
                  *(const i64*)(lds + L_WR + (w*4+kt)*512 + lane*8), xr4);
    __builtin_amdgcn_s_setprio(0);
    {
      unsigned mk = pfA[3];
      f32x4 xu4v = upk4(pfA[2]);
      float xf_[4];
      xf_[0] = bf2f((unsigned short)(pfX[0] & 0xffffu));
      xf_[1] = bf2f((unsigned short)(pfX[0] >> 16));
      xf_[2] = bf2f((unsigned short)(pfX[1] & 0xffffu));
      xf_[3] = bf2f((unsigned short)(pfX[1] >> 16));
      float ims = *(const float*)(lds + L_IMS + t*4);
      float lp = 0.f, xi_[4];
      #pragma unroll
      for (int r = 0; r < 4; ++r){
        int row = lg*4 + r;
        size_t go = ((size_t)(b0+row)*TT + t)*DD + colD;
        float xrv = xr4[r] + br_v;
        __builtin_nontemporal_store(xrv, out_xrs + go);
        float xc = cw0*xu4v[r] + cw1*xrv + cb;
        bool mb = (mk >> r) & 1u;
        lp += mb ? fabsf(xf_[r] - xc) : 0.f;
        xi_[r] = mb ? xf_[r] : xc;
        __builtin_nontemporal_store(xi_[r], out_ximp + go);
      }
      lacc += lp * ims;
      unsigned q = pk4(xi_[0], xi_[1], xi_[2], xi_[3]);
      #pragma unroll
      for (int r = 0; r < 4; ++r)
        *(unsigned char*)(lds + L_XIF + f80 + r*8) = (unsigned char)((q >> (8*r)) & 0xff);
    }
    __syncthreads();  // B3

    // ---------- PH3: gi_x (wihx LDS) + gates + h update ----------
    i64 xia[4];
    #pragma unroll
    for (int kt = 0; kt < 4; ++kt) xia[kt] = *(const i64*)(lds + L_XIF + kt*512 + lane*8);
    __builtin_amdgcn_s_setprio(1);
    #pragma unroll
    for (int s = 0; s < 2; ++s)
      #pragma unroll
      for (int kt = 0; kt < 4; ++kt){
        aRZ[0][s] = mfma8(xia[kt], *(const i64*)(lds + L_WX + ((0*16 + w*2+s)*4 + kt)*512 + lane*8), aRZ[0][s]);
        aRZ[1][s] = mfma8(xia[kt], *(const i64*)(lds + L_WX + ((1*16 + w*2+s)*4 + kt)*512 + lane*8), aRZ[1][s]);
        aNi[s]    = mfma8(xia[kt], *(const i64*)(lds + L_WX + ((2*16 + w*2+s)*4 + kt)*512 + lane*8), aNi[s]);
      }
    __builtin_amdgcn_s_setprio(0);
    {
      f32x4 gR0 = upk4(pfB0[0]), gR1 = upk4(pfB0[1]);
      f32x4 gZ0 = upk4(pfB1[0]), gZ1 = upk4(pfB1[1]);
      f32x4 gN0 = upk4(pfB2[0]), gN1 = upk4(pfB2[1]);
      #pragma unroll
      for (int r = 0; r < 4; ++r){
        float rr0 = sigm(aRZ[0][0][r] + gR0[r]);
        float zz0 = sigm(aRZ[1][0][r] + gZ0[r]);
        float nn0 = tanhfast(aNi[0][r] + gN0[r] + rr0*(aNh[0][r] + bhhn0));
        hs[0][r] = (1.f - zz0)*nn0 + zz0*hs[0][r];
        float rr1 = sigm(aRZ[0][1][r] + gR1[r]);
        float zz1 = sigm(aRZ[1][1][r] + gZ1[r]);
        float nn1 = tanhfast(aNi[1][r] + gN1[r] + rr1*(aNh[1][r] + bhhn1));
        hs[1][r] = (1.f - zz1)*nn1 + zz1*hs[1][r];
      }
    }
    pfA = nA; pfX = nX; pfB0 = nB0; pfB1 = nB1; pfB2 = nB2;
    rpa = npa; rpx = npx; rpb = npb;
  }

  // ---------- epilogue: loss partial + y = h_fin @ W_out^T + b ----------
  __syncthreads();
  #pragma unroll
  for (int off = 32; off >= 1; off >>= 1) lacc += __shfl_down(lacc, off);
  if (lane == 0) red[w] = lacc;
  float* hfin = (float*)lds;
  #pragma unroll
  for (int s = 0; s < 2; ++s)
    #pragma unroll
    for (int r = 0; r < 4; ++r)
      hfin[(lg*4+r)*HH + colH0 + s*16] = hs[s][r];
  __syncthreads();
  if (tid == 0){
    float s = 0.f;
    #pragma unroll
    for (int i = 0; i < NW; ++i) s += red[i];
    lossP[blockIdx.x] = s;
  }
  float* psum = (float*)(lds + 16384);
  if (tid < 256){
    int row = tid >> 4, seg = tid & 15;
    float p = 0.f;
    #pragma unroll
    for (int c = 0; c < 16; ++c) p += hfin[row*HH + seg*16 + c]*W_out[seg*16 + c];
    psum[tid] = p;
  }
  __syncthreads();
  if (tid < 16){
    float yv = b_out[0];
    #pragma unroll
    for (int i = 0; i < 16; ++i) yv += psum[tid*16 + i];
    out_y[b0 + tid] = yv;
    out_ys[b0 + tid] = sigm(yv);
  }
}

extern "C" void kernel_launch(void* const* d_in, const int* in_sizes, int n_in,
                              void* d_out, int out_size, void* d_ws, size_t ws_size,
                              hipStream_t stream){
  const float* x     = (const float*)d_in[0];
  const float* xhat  = (const float*)d_in[1];
  const float* m     = (const float*)d_in[3];
  const float* dly   = (const float*)d_in[4];
  const float* Wdec  = (const float*)d_in[5];
  const float* b_dec = (const float*)d_in[6];
  const float* Whist = (const float*)d_in[7];
  const float* b_hist= (const float*)d_in[8];
  const float* Wv    = (const float*)d_in[9];
  const float* bvv   = (const float*)d_in[10];
  const float* Wr    = (const float*)d_in[11];
  const float* brr   = (const float*)d_in[12];
  const float* convw = (const float*)d_in[13];
  const float* convb = (const float*)d_in[14];
  const float* Wih   = (const float*)d_in[15];
  const float* Whh   = (const float*)d_in[16];
  const float* b_ih  = (const float*)d_in[17];
  const float* b_hh  = (const float*)d_in[18];
  const float* W_out = (const float*)d_in[19];
  const float* b_out = (const float*)d_in[20];

  float* wsf = (float*)d_ws;                 // [0..63] lossP, [8192..8319] inv-msums
  unsigned char* wq = (unsigned char*)d_ws + WS_WQ8;
  unsigned short* wb = (unsigned short*)((char*)d_ws + WS_WB16);
  unsigned* saA = (unsigned*)((char*)d_ws + WS_SA1);
  unsigned* saX = (unsigned*)((char*)d_ws + WS_SAX);
  unsigned* saB = (unsigned*)((char*)d_ws + WS_SA2);

  float* out = (float*)d_out;
  size_t btd = (size_t)BQ*TT*DD;
  float* out_ximp = out;
  float* out_y    = out + btd;
  float* out_ys   = out_y + BQ;
  float* out_loss = out_ys + BQ;
  float* out_xu   = out_loss + 1;
  float* out_xrs  = out_xu + btd;

  (void)hipFuncSetAttribute((const void*)scan_kernel,
                            hipFuncAttributeMaxDynamicSharedMemorySize, L_TOT);

  pack_w8<<<TQ_TOT/4, 256, 0, stream>>>(Whh, Wih, Whist, Wr, wq);
  pack_w16<<<TB_TOT/4, 256, 0, stream>>>(Wdec, Wv, wb);
  msum_kernel<<<TT, 256, 0, stream>>>(m, wsf);
  prep_kernel<<<1024, 512, 0, stream>>>(x, xhat, m, dly, b_dec, bvv, b_ih, b_hh,
      wb, wq, saA, saX, saB, out_xu);
  scan_kernel<<<NBLK, NTH, L_TOT, stream>>>(wq, saA, saX, saB, wsf + WS_MSUMF,
      b_hist, brr, b_hh, convw, convb, W_out, b_out, wsf,
      out_ximp, out_y, out_ys, out_xrs);
  loss_final<<<1, 64, 0, stream>>>(wsf, out_loss);
}